// Round 6
// baseline (653.201 us; speedup 1.0000x reference)
//
#include <hip/hip_runtime.h>

namespace {

constexpr int SEQ = 2048, BATCH = 1024, IN = 10, H = 20;
constexpr int XS  = 32;                  // x steps per LDS chunk
constexpr int XROW = 12;                 // padded floats per step-row (10 used) -> 48B, 16B-aligned
constexpr float L2E = 1.4426950408889634f;

typedef _Float16 h2t __attribute__((ext_vector_type(2)));

__device__ __forceinline__ float rcpf(float x) { return __builtin_amdgcn_rcpf(x); }
__device__ __forceinline__ float xp2(float x)  { return __builtin_amdgcn_exp2f(x); }

__device__ __forceinline__ int pk(float a, float b) {
    auto v = __builtin_amdgcn_cvt_pkrtz(a, b);
    int i; __builtin_memcpy(&i, &v, 4); return i;
}
__device__ __forceinline__ float dot2(int a, int b, float c) {
    h2t ha, hb; __builtin_memcpy(&ha, &a, 4); __builtin_memcpy(&hb, &b, 4);
    return __builtin_amdgcn_fdot2(ha, hb, c, false);
}
// value from lane^1 (quad_perm [1,0,3,2] = dpp_ctrl 0xB1), all lanes active
__device__ __forceinline__ float dpp_x1(float v) {
    int i; __builtin_memcpy(&i, &v, 4);
    int r = __builtin_amdgcn_update_dpp(0, i, 0xB1, 0xF, 0xF, true);
    float f; __builtin_memcpy(&f, &r, 4); return f;
}

__launch_bounds__(64)
__global__ void lstm_bidir(const float* __restrict__ x,
                           const float* __restrict__ h0,
                           const float* __restrict__ c0,
                           const float* __restrict__ w_ih_f, const float* __restrict__ w_hh_f,
                           const float* __restrict__ b_ih_f, const float* __restrict__ b_hh_f,
                           const float* __restrict__ w_ih_b, const float* __restrict__ w_hh_b,
                           const float* __restrict__ b_ih_b, const float* __restrict__ b_hh_b,
                           float* __restrict__ out, float* __restrict__ h_n, float* __restrict__ c_n)
{
    const int dir  = blockIdx.y;
    const int b    = blockIdx.x;          // one batch element per (one-wave) block
    const int lane = threadIdx.x;
    const int u    = lane >> 1;           // unit 0..31 (20..31 junk, clamped)
    const int gp   = lane & 1;            // 0: gates {i,f}, 1: gates {g~,o}
    const int ur   = (u < H) ? u : (H - 1);
    const bool red = (gp == 0) && (u < H);   // result lanes (one per unit)

    const float* w_ih = dir ? w_ih_b : w_ih_f;
    const float* w_hh = dir ? w_hh_b : w_hh_f;
    const float* bi   = dir ? b_ih_b : b_ih_f;
    const float* bh   = dir ? b_hh_b : b_hh_f;

    __shared__ __align__(16) float    xlds[2][XS * XROW];   // 3 KiB
    __shared__ __align__(16) _Float16 hlds[32];             // h exchange (20 used)

    // ---- this lane's two gate rows, fp16-packed, pre-scaled by -log2e (tanh row: -2log2e) ----
    // gate0 = row gp*2H+u  (i or g~), gate1 = row gp*2H+H+u  (f or o)
    const int g0 = gp * 2 * H + ur, g1 = g0 + H;
    const float sc0 = gp ? (-2.0f * L2E) : (-L2E);
    const float sc1 = -L2E;
    const float na0 = gp ? 2.0f : 1.0f;            // tanh = 2*sig-1
    const float nd0 = gp ? -1.0f : 0.0f;

    int wh[2][10], wi[2][5]; float bias[2];
    #pragma unroll
    for (int k = 0; k < 10; ++k) {
        wh[0][k] = pk(w_hh[g0 * H + 2 * k] * sc0, w_hh[g0 * H + 2 * k + 1] * sc0);
        wh[1][k] = pk(w_hh[g1 * H + 2 * k] * sc1, w_hh[g1 * H + 2 * k + 1] * sc1);
    }
    #pragma unroll
    for (int k = 0; k < 5; ++k) {
        wi[0][k] = pk(w_ih[g0 * IN + 2 * k] * sc0, w_ih[g0 * IN + 2 * k + 1] * sc0);
        wi[1][k] = pk(w_ih[g1 * IN + 2 * k] * sc1, w_ih[g1 * IN + 2 * k + 1] * sc1);
    }
    bias[0] = (bi[g0] + bh[g0]) * sc0;
    bias[1] = (bi[g1] + bh[g1]) * sc1;

    float c  = c0[(dir * BATCH + b) * H + ur];
    float hv = h0[(dir * BATCH + b) * H + ur];
    hlds[u] = (_Float16)hv;                        // init exchange buffer

    // ---- x chunk staging: 320 floats/chunk, 5 per lane (e = lane + 64i), padded rows of 12 ----
    const float*    xbase = x + (size_t)(dir ? SEQ - 1 : 0) * (BATCH * IN) + b * IN;
    const ptrdiff_t xstep = dir ? -(ptrdiff_t)(BATCH * IN) : (ptrdiff_t)(BATCH * IN);

    const float* xaddr[5];  int wadd[5];
    #pragma unroll
    for (int i = 0; i < 5; ++i) {
        const int e = lane + 64 * i;               // 0..319
        xaddr[i] = xbase + (ptrdiff_t)(e / 10) * xstep + (e % 10);
        wadd[i]  = (e / 10) * XROW + (e % 10);
    }
    float pend[5];
    auto issue_chunk = [&]() {
        #pragma unroll
        for (int i = 0; i < 5; ++i) pend[i] = *xaddr[i];
        #pragma unroll
        for (int i = 0; i < 5; ++i) xaddr[i] += XS * xstep;   // advance (may run past end; never consumed)
    };
    auto write_chunk = [&](int buf) {
        float* dst = &xlds[buf][0];
        #pragma unroll
        for (int i = 0; i < 5; ++i) dst[wadd[i]] = pend[i];
    };

    issue_chunk();  write_chunk(0);
    issue_chunk();                                  // next chunk pending in regs

    float*          optr  = out + (size_t)(dir ? SEQ - 1 : 0) * (BATCH * 2 * H) + b * (2 * H) + dir * H + ur;
    const ptrdiff_t ostep = dir ? -(ptrdiff_t)(BATCH * 2 * H) : (ptrdiff_t)(BATCH * 2 * H);

    for (int s0 = 0; s0 < SEQ; s0 += XS) {
        const int buf = (s0 >> 5) & 1;
        const float* xrowp = &xlds[buf][0];
        for (int ss = 0; ss < XS; ++ss) {
            // ---- read h pairs (wave-uniform broadcast, 40B) and x row (48B-aligned) ----
            const int4 hA = *(const int4*)(&hlds[0]);        // pairs 0..3
            const int4 hB = *(const int4*)(&hlds[8]);        // pairs 4..7
            const int2 hC = *(const int2*)(&hlds[16]);       // pairs 8,9
            const float4 xa = *(const float4*)(xrowp);
            const float4 xb = *(const float4*)(xrowp + 4);
            const float2 xc = *(const float2*)(xrowp + 8);
            xrowp += XROW;

            int hp[10] = { hA.x, hA.y, hA.z, hA.w, hB.x, hB.y, hB.z, hB.w, hC.x, hC.y };
            int xq[5]  = { pk(xa.x, xa.y), pk(xa.z, xa.w), pk(xb.x, xb.y), pk(xb.z, xb.w), pk(xc.x, xc.y) };

            // ---- 2 gates per lane: 15 dot2 each ----
            float a0 = bias[0], a1 = bias[1];
            #pragma unroll
            for (int k = 0; k < 10; ++k) { a0 = dot2(hp[k], wh[0][k], a0); a1 = dot2(hp[k], wh[1][k], a1); }
            #pragma unroll
            for (int k = 0; k < 5;  ++k) { a0 = dot2(xq[k], wi[0][k], a0); a1 = dot2(xq[k], wi[1][k], a1); }

            // ---- nonlinearities (per-lane consts make i/f/g~/o uniform) ----
            const float n0 = fmaf(na0, rcpf(1.0f + xp2(a0)), nd0);   // gp0: sig(i)  gp1: tanh(g~)
            const float n1 = rcpf(1.0f + xp2(a1));                   // gp0: sig(f)  gp1: sig(o)

            // ---- gate-pair exchange via DPP lane^1 (VALU, no LDS) ----
            const float m0 = dpp_x1(n0);
            const float m1 = dpp_x1(n1);
            const float gi = gp ? m0 : n0;
            const float gf = gp ? m1 : n1;
            const float gt = gp ? n0 : m0;
            const float go = gp ? n1 : m1;

            c = fmaf(gf, c, gi * gt);
            const float th = fmaf(2.0f, rcpf(1.0f + xp2(c * (-2.0f * L2E))), -1.0f);
            hv = go * th;

            hlds[u] = (_Float16)hv;                 // publish for next step (in-order DS pipe)
            if (red) __builtin_nontemporal_store(hv, optr);
            optr += ostep;
        }
        // ---- chunk boundary: publish pending chunk, prefetch next-next ----
        if (s0 + XS < SEQ) {
            write_chunk(buf ^ 1);                   // counted-vmcnt wait on old loads only
            if (s0 + 2 * XS < SEQ) issue_chunk();
        }
    }

    if (red) {
        h_n[(dir * BATCH + b) * H + ur] = hv;
        c_n[(dir * BATCH + b) * H + ur] = c;
    }
}

} // namespace

extern "C" void kernel_launch(void* const* d_in, const int* in_sizes, int n_in,
                              void* d_out, int out_size, void* d_ws, size_t ws_size,
                              hipStream_t stream)
{
    const float* x      = (const float*)d_in[0];
    const float* h0     = (const float*)d_in[1];
    const float* c0     = (const float*)d_in[2];
    const float* w_ih_f = (const float*)d_in[3];
    const float* w_hh_f = (const float*)d_in[4];
    const float* b_ih_f = (const float*)d_in[5];
    const float* b_hh_f = (const float*)d_in[6];
    const float* w_ih_b = (const float*)d_in[7];
    const float* w_hh_b = (const float*)d_in[8];
    const float* b_ih_b = (const float*)d_in[9];
    const float* b_hh_b = (const float*)d_in[10];

    float* out = (float*)d_out;
    float* h_n = out + (size_t)SEQ * BATCH * 2 * H;
    float* c_n = h_n + (size_t)2 * BATCH * H;

    dim3 grid(BATCH, 2), block(64);
    hipLaunchKernelGGL(lstm_bidir, grid, block, 0, stream,
                       x, h0, c0, w_ih_f, w_hh_f, b_ih_f, b_hh_f,
                       w_ih_b, w_hh_b, b_ih_b, b_hh_b, out, h_n, c_n);
}

// Round 7
// 638.266 us; speedup vs baseline: 1.0234x; 1.0234x over previous
//
#include <hip/hip_runtime.h>

namespace {

constexpr int SEQ = 2048, BATCH = 1024, IN = 10, H = 20;
constexpr int XS  = 32;                  // x steps per LDS chunk
constexpr int XRW = 8;                   // ints per step-row in LDS (5 used) -> 32B, b128-aligned
constexpr float L2E = 1.4426950408889634f;

typedef _Float16 h2t __attribute__((ext_vector_type(2)));

__device__ __forceinline__ float rcpf(float x) { return __builtin_amdgcn_rcpf(x); }
__device__ __forceinline__ float xp2(float x)  { return __builtin_amdgcn_exp2f(x); }

__device__ __forceinline__ int pk(float a, float b) {
    auto v = __builtin_amdgcn_cvt_pkrtz(a, b);
    int i; __builtin_memcpy(&i, &v, 4); return i;
}
__device__ __forceinline__ float dot2(int a, int b, float c) {
    h2t ha, hb; __builtin_memcpy(&ha, &a, 4); __builtin_memcpy(&hb, &b, 4);
    return __builtin_amdgcn_fdot2(ha, hb, c, false);
}
// value from lane^1 (quad_perm [1,0,3,2] = 0xB1)
__device__ __forceinline__ float dpp_x1(float v) {
    int i; __builtin_memcpy(&i, &v, 4);
    int r = __builtin_amdgcn_update_dpp(0, i, 0xB1, 0xF, 0xF, true);
    float f; __builtin_memcpy(&f, &r, 4); return f;
}
// value from lane^2 (quad_perm [2,3,0,1] = 0x4E)
__device__ __forceinline__ float dpp_x2(float v) {
    int i; __builtin_memcpy(&i, &v, 4);
    int r = __builtin_amdgcn_update_dpp(0, i, 0x4E, 0xF, 0xF, true);
    float f; __builtin_memcpy(&f, &r, 4); return f;
}

__launch_bounds__(64)
__global__ void lstm_bidir(const float* __restrict__ x,
                           const float* __restrict__ h0,
                           const float* __restrict__ c0,
                           const float* __restrict__ w_ih_f, const float* __restrict__ w_hh_f,
                           const float* __restrict__ b_ih_f, const float* __restrict__ b_hh_f,
                           const float* __restrict__ w_ih_b, const float* __restrict__ w_hh_b,
                           const float* __restrict__ b_ih_b, const float* __restrict__ b_hh_b,
                           float* __restrict__ out, float* __restrict__ h_n, float* __restrict__ c_n)
{
    const int dir  = blockIdx.y;
    const int b    = blockIdx.x;          // one batch element per (one-wave) block
    const int lane = threadIdx.x;
    const int u    = lane >> 1;           // unit 0..31 (20..31 junk, clamped)
    const int gp   = lane & 1;            // 0: gates {i,f}, 1: gates {g~,o}
    const int ur   = (u < H) ? u : (H - 1);
    const bool red = (gp == 0) && (u < H);   // result lanes (one per unit)

    const float* w_ih = dir ? w_ih_b : w_ih_f;
    const float* w_hh = dir ? w_hh_b : w_hh_f;
    const float* bi   = dir ? b_ih_b : b_ih_f;
    const float* bh   = dir ? b_hh_b : b_hh_f;

    __shared__ __align__(16) int xlds[2][XS * XRW];   // x chunks, fp16-pair packed (2 KiB)

    // ---- this lane's two gate rows, fp16-packed, pre-scaled by -log2e (tanh row: -2log2e) ----
    const int g0 = gp * 2 * H + ur, g1 = g0 + H;      // gp0: {i,f}, gp1: {g~,o}
    const float sc0 = gp ? (-2.0f * L2E) : (-L2E);
    const float sc1 = -L2E;
    const float na0 = gp ? 2.0f : 1.0f;               // tanh = 2*sig-1
    const float nd0 = gp ? -1.0f : 0.0f;

    int wh[2][10], wi[2][5]; float bias[2];
    #pragma unroll
    for (int k = 0; k < 10; ++k) {
        wh[0][k] = pk(w_hh[g0 * H + 2 * k] * sc0, w_hh[g0 * H + 2 * k + 1] * sc0);
        wh[1][k] = pk(w_hh[g1 * H + 2 * k] * sc1, w_hh[g1 * H + 2 * k + 1] * sc1);
    }
    #pragma unroll
    for (int k = 0; k < 5; ++k) {
        wi[0][k] = pk(w_ih[g0 * IN + 2 * k] * sc0, w_ih[g0 * IN + 2 * k + 1] * sc0);
        wi[1][k] = pk(w_ih[g1 * IN + 2 * k] * sc1, w_ih[g1 * IN + 2 * k + 1] * sc1);
    }
    bias[0] = (bi[g0] + bh[g0]) * sc0;
    bias[1] = (bi[g1] + bh[g1]) * sc1;

    float c  = c0[(dir * BATCH + b) * H + ur];
    float hv = h0[(dir * BATCH + b) * H + ur];

    // ---- x chunk staging: 160 fp16-pairs/chunk, packed at stage time ----
    // pair e (e=0..159): step ss=e/5, pair j=e%5 -> global float2 at row(s0+ss), col b*10+2j
    const float*    xbase = x + b * IN;
    const ptrdiff_t xstep = dir ? -(ptrdiff_t)(BATCH * IN) : (ptrdiff_t)(BATCH * IN);
    const size_t    xoff0 = (size_t)(dir ? SEQ - 1 : 0) * (BATCH * IN);

    float2 pend[3];
    auto issue_chunk = [&](int s0) {
        #pragma unroll
        for (int i = 0; i < 3; ++i) {
            const int e = lane + 64 * i;
            if (i < 2 || lane < 32) {              // e < 160
                const int ss = e / 5, j = e % 5;
                pend[i] = *(const float2*)(xbase + xoff0 + (ptrdiff_t)(s0 + ss) * xstep + 2 * j);
            }
        }
    };
    auto write_chunk = [&](int buf) {
        #pragma unroll
        for (int i = 0; i < 3; ++i) {
            const int e = lane + 64 * i;
            if (i < 2 || lane < 32)
                xlds[buf][(e / 5) * XRW + (e % 5)] = pk(pend[i].x, pend[i].y);
        }
    };

    issue_chunk(0);  write_chunk(0);
    issue_chunk(XS);                                // next chunk pending in regs

    float*          optr  = out + (size_t)(dir ? SEQ - 1 : 0) * (BATCH * 2 * H) + b * (2 * H) + dir * H + ur;
    const ptrdiff_t ostep = dir ? -(ptrdiff_t)(BATCH * 2 * H) : (ptrdiff_t)(BATCH * 2 * H);

    for (int s0 = 0; s0 < SEQ; s0 += XS) {
        const int buf = (s0 >> 5) & 1;
        for (int ss = 0; ss < XS; ++ss) {
            // ---- h broadcast to SGPRs: pair via DPP lane^2 + pk on lanes 4k, readlane x10 ----
            // lane 4k holds h_{2k}; lane 4k+2 holds h_{2k+1}
            const float hx   = dpp_x2(hv);
            const int   hpair = pk(hv, hx);          // valid on lanes 0,4,...,36
            int hs[10];
            #pragma unroll
            for (int k = 0; k < 10; ++k)
                hs[k] = __builtin_amdgcn_readlane(hpair, 4 * k);

            // ---- x row: fp16 pairs straight from LDS (wave-uniform broadcast) ----
            const int* xr = &xlds[buf][ss * XRW];
            const int4 xA = *(const int4*)xr;        // pairs 0..3 (32B-aligned)
            const int  x4 = xr[4];                   // pair 4
            const int  xq[5] = { xA.x, xA.y, xA.z, xA.w, x4 };

            // ---- 2 gates per lane, 2 partial accs each (4 independent dot2 chains) ----
            float a0 = bias[0], a1 = bias[1], p0 = 0.0f, p1 = 0.0f;
            #pragma unroll
            for (int k = 0; k < 5; ++k) {
                a0 = dot2(hs[k],     wh[0][k],     a0);
                a1 = dot2(hs[k],     wh[1][k],     a1);
                p0 = dot2(hs[k + 5], wh[0][k + 5], p0);
                p1 = dot2(hs[k + 5], wh[1][k + 5], p1);
            }
            #pragma unroll
            for (int k = 0; k < 3; ++k) {
                a0 = dot2(xq[k], wi[0][k], a0);
                a1 = dot2(xq[k], wi[1][k], a1);
            }
            #pragma unroll
            for (int k = 3; k < 5; ++k) {
                p0 = dot2(xq[k], wi[0][k], p0);
                p1 = dot2(xq[k], wi[1][k], p1);
            }
            a0 += p0;  a1 += p1;

            // ---- nonlinearities (per-lane consts make i/f/g~/o uniform) ----
            const float n0 = fmaf(na0, rcpf(1.0f + xp2(a0)), nd0);   // gp0: sig(i)  gp1: tanh(g~)
            const float n1 = rcpf(1.0f + xp2(a1));                   // gp0: sig(f)  gp1: sig(o)

            // ---- gate-pair exchange via DPP lane^1 (VALU, no LDS) ----
            const float m0 = dpp_x1(n0);
            const float m1 = dpp_x1(n1);
            const float gi = gp ? m0 : n0;
            const float gf = gp ? m1 : n1;
            const float gt = gp ? n0 : m0;
            const float go = gp ? n1 : m1;

            c = fmaf(gf, c, gi * gt);
            const float th = fmaf(2.0f, rcpf(1.0f + xp2(c * (-2.0f * L2E))), -1.0f);
            hv = go * th;

            if (red) __builtin_nontemporal_store(hv, optr);
            optr += ostep;
        }
        // ---- chunk boundary: publish pending chunk, prefetch next-next ----
        if (s0 + XS < SEQ) {
            write_chunk(buf ^ 1);                   // counted-vmcnt wait on old loads only
            if (s0 + 2 * XS < SEQ) issue_chunk(s0 + 2 * XS);
        }
    }

    if (red) {
        h_n[(dir * BATCH + b) * H + ur] = hv;
        c_n[(dir * BATCH + b) * H + ur] = c;
    }
}

} // namespace

extern "C" void kernel_launch(void* const* d_in, const int* in_sizes, int n_in,
                              void* d_out, int out_size, void* d_ws, size_t ws_size,
                              hipStream_t stream)
{
    const float* x      = (const float*)d_in[0];
    const float* h0     = (const float*)d_in[1];
    const float* c0     = (const float*)d_in[2];
    const float* w_ih_f = (const float*)d_in[3];
    const float* w_hh_f = (const float*)d_in[4];
    const float* b_ih_f = (const float*)d_in[5];
    const float* b_hh_f = (const float*)d_in[6];
    const float* w_ih_b = (const float*)d_in[7];
    const float* w_hh_b = (const float*)d_in[8];
    const float* b_ih_b = (const float*)d_in[9];
    const float* b_hh_b = (const float*)d_in[10];

    float* out = (float*)d_out;
    float* h_n = out + (size_t)SEQ * BATCH * 2 * H;
    float* c_n = h_n + (size_t)2 * BATCH * H;

    dim3 grid(BATCH, 2), block(64);
    hipLaunchKernelGGL(lstm_bidir, grid, block, 0, stream,
                       x, h0, c0, w_ih_f, w_hh_f, b_ih_f, b_hh_f,
                       w_ih_b, w_hh_b, b_ih_b, b_hh_b, out, h_n, c_n);
}

// Round 8
// 567.916 us; speedup vs baseline: 1.1502x; 1.1239x over previous
//
#include <hip/hip_runtime.h>

namespace {

constexpr int SEQ = 2048, BATCH = 1024, IN = 10, H = 20;
constexpr int XS  = 32;                  // x steps per LDS chunk
constexpr int XRW = 8;                   // ints per step-row in LDS (5 used) -> 32B, b128-aligned
constexpr float L2E = 1.4426950408889634f;
constexpr float K2  = -2.0f * L2E;       // carried scale on c:  c' = K2 * c

typedef _Float16 h2t __attribute__((ext_vector_type(2)));

__device__ __forceinline__ float rcpf(float x) { return __builtin_amdgcn_rcpf(x); }
__device__ __forceinline__ float xp2(float x)  { return __builtin_amdgcn_exp2f(x); }

__device__ __forceinline__ int pk(float a, float b) {
    auto v = __builtin_amdgcn_cvt_pkrtz(a, b);
    int i; __builtin_memcpy(&i, &v, 4); return i;
}
__device__ __forceinline__ float dot2(int a, int b, float c) {
    h2t ha, hb; __builtin_memcpy(&ha, &a, 4); __builtin_memcpy(&hb, &b, 4);
    return __builtin_amdgcn_fdot2(ha, hb, c, false);
}
// lane^1 (quad_perm [1,0,3,2] = 0xB1)
__device__ __forceinline__ float dpp_x1(float v) {
    int i; __builtin_memcpy(&i, &v, 4);
    int r = __builtin_amdgcn_update_dpp(0, i, 0xB1, 0xF, 0xF, true);
    float f; __builtin_memcpy(&f, &r, 4); return f;
}
// lane^2 (quad_perm [2,3,0,1] = 0x4E)
__device__ __forceinline__ float dpp_x2(float v) {
    int i; __builtin_memcpy(&i, &v, 4);
    int r = __builtin_amdgcn_update_dpp(0, i, 0x4E, 0xF, 0xF, true);
    float f; __builtin_memcpy(&f, &r, 4); return f;
}

__launch_bounds__(64)
__global__ void lstm_bidir(const float* __restrict__ x,
                           const float* __restrict__ h0,
                           const float* __restrict__ c0,
                           const float* __restrict__ w_ih_f, const float* __restrict__ w_hh_f,
                           const float* __restrict__ b_ih_f, const float* __restrict__ b_hh_f,
                           const float* __restrict__ w_ih_b, const float* __restrict__ w_hh_b,
                           const float* __restrict__ b_ih_b, const float* __restrict__ b_hh_b,
                           float* __restrict__ out, float* __restrict__ h_n, float* __restrict__ c_n)
{
    const int dir  = blockIdx.y;
    const int b    = blockIdx.x;          // one chain per one-wave block
    const int lane = threadIdx.x;
    const int u    = lane >> 1;           // unit 0..31 (20..31 junk, clamped)
    const int gp   = lane & 1;            // 0: gates {i,f}, 1: gates {g~,o}
    const int ur   = (u < H) ? u : (H - 1);
    const bool red = (gp == 0) && (u < H);

    const float* w_ih = dir ? w_ih_b : w_ih_f;
    const float* w_hh = dir ? w_hh_b : w_hh_f;
    const float* bi   = dir ? b_ih_b : b_ih_f;
    const float* bh   = dir ? b_hh_b : b_hh_f;

    __shared__ __align__(16) int xlds[2][XS * XRW];   // x chunks, fp16-pair packed
    __shared__ __align__(16) int hl[96];              // [0..9] h pairs, [16..79] dump

    // ---- gate rows in registers, fp16-packed, pre-scaled by -log2e (tanh row: -2log2e) ----
    const int g0 = gp * 2 * H + ur, g1 = g0 + H;      // gp0: {i,f}, gp1: {g~,o}
    const float sc0 = gp ? K2 : (-L2E);
    const float sc1 = -L2E;
    // post-nonlin: gp0.n0 = sigmoid(i); gp1.n0 = K2*tanh(g~)  (K2 folded so c-update has no extra mul)
    const float na0 = gp ? (2.0f * K2) : 1.0f;
    const float nd0 = gp ? (-K2) : 0.0f;

    int wh[2][10], wi[2][5]; float bias[2];
    #pragma unroll
    for (int k = 0; k < 10; ++k) {
        wh[0][k] = pk(w_hh[g0 * H + 2 * k] * sc0, w_hh[g0 * H + 2 * k + 1] * sc0);
        wh[1][k] = pk(w_hh[g1 * H + 2 * k] * sc1, w_hh[g1 * H + 2 * k + 1] * sc1);
    }
    #pragma unroll
    for (int k = 0; k < 5; ++k) {
        wi[0][k] = pk(w_ih[g0 * IN + 2 * k] * sc0, w_ih[g0 * IN + 2 * k + 1] * sc0);
        wi[1][k] = pk(w_ih[g1 * IN + 2 * k] * sc1, w_ih[g1 * IN + 2 * k + 1] * sc1);
    }
    bias[0] = (bi[g0] + bh[g0]) * sc0;
    bias[1] = (bi[g1] + bh[g1]) * sc1;

    float c  = c0[(dir * BATCH + b) * H + ur] * K2;   // carried pre-scaled
    float hv = h0[(dir * BATCH + b) * H + ur];

    // ---- h publish: lanes 4k,4k+1 hold a valid (h2k,h2k+1) pair after dpp_x2 ----
    const bool wok  = ((lane & 2) == 0) && (u < H);
    const int  hoff = wok ? (lane >> 2) : (16 + lane);   // junk lanes -> distinct dump slots
    hl[hoff] = pk(hv, dpp_x2(hv));                       // initial publish

    // ---- x chunk staging: 160 fp16-pairs/chunk, packed at stage time ----
    const float*    xbase = x + b * IN;
    const ptrdiff_t xstep = dir ? -(ptrdiff_t)(BATCH * IN) : (ptrdiff_t)(BATCH * IN);
    const size_t    xoff0 = (size_t)(dir ? SEQ - 1 : 0) * (BATCH * IN);

    float2 pend[3];
    auto issue_chunk = [&](int s0) {
        #pragma unroll
        for (int i = 0; i < 3; ++i) {
            const int e = lane + 64 * i;
            if (i < 2 || lane < 32) {              // e < 160
                const int ss = e / 5, j = e % 5;
                pend[i] = *(const float2*)(xbase + xoff0 + (ptrdiff_t)(s0 + ss) * xstep + 2 * j);
            }
        }
    };
    auto write_chunk = [&](int buf) {
        #pragma unroll
        for (int i = 0; i < 3; ++i) {
            const int e = lane + 64 * i;
            if (i < 2 || lane < 32)
                xlds[buf][(e / 5) * XRW + (e % 5)] = pk(pend[i].x, pend[i].y);
        }
    };

    issue_chunk(0);  write_chunk(0);
    issue_chunk(XS);                                // next chunk pending in regs

    float*          optr  = out + (size_t)(dir ? SEQ - 1 : 0) * (BATCH * 2 * H) + b * (2 * H) + dir * H + ur;
    const ptrdiff_t ostep = dir ? -(ptrdiff_t)(BATCH * 2 * H) : (ptrdiff_t)(BATCH * 2 * H);

    for (int s0 = 0; s0 < SEQ; s0 += XS) {
        const int buf = (s0 >> 5) & 1;
        #pragma unroll 4
        for (int ss = 0; ss < XS; ++ss) {
            // ---- x row (wave-uniform broadcast, pre-packed fp16 pairs) ----
            const int* xr = &xlds[buf][ss * XRW];
            const int4 xA = *(const int4*)xr;
            const int  x4 = xr[4];
            const int  xq[5] = { xA.x, xA.y, xA.z, xA.w, x4 };

            // ---- h pairs (wave-uniform broadcast; previous step's in-order DS write) ----
            const int4 hA = *(const int4*)&hl[0];
            const int4 hB = *(const int4*)&hl[4];
            const int2 hC = *(const int2*)&hl[8];
            const int  hp[10] = { hA.x, hA.y, hA.z, hA.w, hB.x, hB.y, hB.z, hB.w, hC.x, hC.y };

            // ---- 2 gates per lane, split accumulators (4 independent dot2 chains) ----
            float a0 = bias[0], a1 = bias[1], p0 = 0.0f, p1 = 0.0f;
            #pragma unroll
            for (int k = 0; k < 3; ++k) {
                a0 = dot2(xq[k], wi[0][k], a0);
                a1 = dot2(xq[k], wi[1][k], a1);
            }
            #pragma unroll
            for (int k = 3; k < 5; ++k) {
                p0 = dot2(xq[k], wi[0][k], p0);
                p1 = dot2(xq[k], wi[1][k], p1);
            }
            #pragma unroll
            for (int k = 0; k < 5; ++k) {
                a0 = dot2(hp[k],     wh[0][k],     a0);
                a1 = dot2(hp[k],     wh[1][k],     a1);
                p0 = dot2(hp[k + 5], wh[0][k + 5], p0);
                p1 = dot2(hp[k + 5], wh[1][k + 5], p1);
            }
            a0 += p0;  a1 += p1;

            // ---- nonlinearities ----
            const float n0 = fmaf(na0, rcpf(1.0f + xp2(a0)), nd0);  // gp0: sig(i)   gp1: K2*tanh(g~)
            const float n1 = rcpf(1.0f + xp2(a1));                  // gp0: sig(f)   gp1: sig(o)

            // ---- gate-pair exchange: 2 DPP + 2 selects (i*g product is lane-symmetric) ----
            const float m0 = dpp_x1(n0);
            const float m1 = dpp_x1(n1);
            const float F  = gp ? m1 : n1;            // sig(f)
            c = fmaf(F, c, n0 * m0);                  // c' = F*c' + K2*sig(i)*tanh(g~)
            const float th = fmaf(2.0f, rcpf(1.0f + xp2(c)), -1.0f);  // tanh(c) since c'=K2*c
            const float o  = gp ? n1 : m1;            // sig(o)
            hv = o * th;

            hl[hoff] = pk(hv, dpp_x2(hv));            // publish for next step (in-order DS)
            if (red) __builtin_nontemporal_store(hv, optr);
            optr += ostep;
        }
        // ---- chunk boundary: publish pending chunk, prefetch next-next ----
        if (s0 + XS < SEQ) {
            write_chunk(buf ^ 1);                     // counted-vmcnt wait on old loads only
            if (s0 + 2 * XS < SEQ) issue_chunk(s0 + 2 * XS);
        }
    }

    if (red) {
        h_n[(dir * BATCH + b) * H + ur] = hv;
        c_n[(dir * BATCH + b) * H + ur] = c * (1.0f / K2);
    }
}

} // namespace

extern "C" void kernel_launch(void* const* d_in, const int* in_sizes, int n_in,
                              void* d_out, int out_size, void* d_ws, size_t ws_size,
                              hipStream_t stream)
{
    const float* x      = (const float*)d_in[0];
    const float* h0     = (const float*)d_in[1];
    const float* c0     = (const float*)d_in[2];
    const float* w_ih_f = (const float*)d_in[3];
    const float* w_hh_f = (const float*)d_in[4];
    const float* b_ih_f = (const float*)d_in[5];
    const float* b_hh_f = (const float*)d_in[6];
    const float* w_ih_b = (const float*)d_in[7];
    const float* w_hh_b = (const float*)d_in[8];
    const float* b_ih_b = (const float*)d_in[9];
    const float* b_hh_b = (const float*)d_in[10];

    float* out = (float*)d_out;
    float* h_n = out + (size_t)SEQ * BATCH * 2 * H;
    float* c_n = h_n + (size_t)2 * BATCH * H;

    dim3 grid(BATCH, 2), block(64);
    hipLaunchKernelGGL(lstm_bidir, grid, block, 0, stream,
                       x, h0, c0, w_ih_f, w_hh_f, b_ih_f, b_hh_f,
                       w_ih_b, w_hh_b, b_ih_b, b_hh_b, out, h_n, c_n);
}